// Round 1
// 1916.379 us; speedup vs baseline: 3.1190x; 3.1190x over previous
//
#include <hip/hip_runtime.h>
#include <hip/hip_bf16.h>

#define Bn   8
#define Sn   1024
#define HIDn 768
#define NHn  12
#define HDn  64
#define MROWS (Bn * Sn)              // 8192
#define OUT0  ((size_t)MROWS * HIDn) // 6291456

typedef __attribute__((ext_vector_type(8))) short short8;
typedef __attribute__((ext_vector_type(4))) float f32x4;

__device__ __forceinline__ float bf2f(unsigned short u) {
    union { unsigned int i; float f; } v;
    v.i = ((unsigned int)u) << 16;
    return v.f;
}
__device__ __forceinline__ unsigned short f2bf(float f) {
    __hip_bfloat16 h = __float2bfloat16(f);
    return *reinterpret_cast<unsigned short*>(&h);
}

template <typename T> struct Ld;
template <> struct Ld<unsigned short> {
    static __device__ __forceinline__ void load8(const unsigned short* src, float* d) {
        uint4 v = *(const uint4*)src;
        const unsigned short* us = (const unsigned short*)&v;
        #pragma unroll
        for (int t = 0; t < 8; ++t) d[t] = bf2f(us[t]);
    }
    static __device__ __forceinline__ float ld1(const unsigned short* p) { return bf2f(*p); }
};
template <> struct Ld<float> {
    static __device__ __forceinline__ void load8(const float* src, float* d) {
        float4 a = *(const float4*)src;
        float4 b = *(const float4*)(src + 4);
        d[0] = a.x; d[1] = a.y; d[2] = a.z; d[3] = a.w;
        d[4] = b.x; d[5] = b.y; d[6] = b.z; d[7] = b.w;
    }
    static __device__ __forceinline__ float ld1(const float* p) { return *p; }
};

// dtype probe: even-index ushorts of fp32 data are random low-mantissa bits
// (~45% insane as bf16); of bf16 data they are sane values. flag: 1=fp32, 0=bf16.
__global__ void probe_kernel(const unsigned short* __restrict__ q, int* __restrict__ flag) {
    __shared__ int cnt;
    if (threadIdx.x == 0) cnt = 0;
    __syncthreads();
    int ins = 0;
    for (int i = threadIdx.x; i < 4096; i += 256) {
        unsigned short u = q[2 * i];
        int e = (u >> 7) & 0xFF;
        float v = bf2f(u);
        if (e == 0xFF || fabsf(v) > 1e4f) ins++;
    }
    atomicAdd(&cnt, ins);
    __syncthreads();
    if (threadIdx.x == 0) *flag = (cnt > 400) ? 1 : 0;
}

// Tiled GEMM: C = A_cat @ W + bias, optional sigmoid(gate)*(.) epilogue.
template <typename TA, typename TA2, typename TW>
__launch_bounds__(256)
__global__ void gemm_kernel(const TA*  __restrict__ A,
                            const TA2* __restrict__ A2,
                            int Ksplit, int K,
                            const TW* __restrict__ W,
                            const TW* __restrict__ bias,
                            const unsigned short* __restrict__ gate,
                            void* __restrict__ Cv, int c_fp32,
                            const int* __restrict__ flag, int mymode)
{
    if (*flag != mymode) return;

    __shared__ float As[64][33];
    __shared__ float Bs[32][64];

    const int tid = threadIdx.x;
    const int tx = tid & 15, ty = tid >> 4;
    const int n0 = blockIdx.x * 64;
    const int m0 = blockIdx.y * 64;

    const int ar = tid >> 2;
    const int ac = (tid & 3) * 8;
    const int br = tid >> 3;
    const int bc = (tid & 7) * 8;

    float acc[4][4] = {};

    for (int k0 = 0; k0 < K; k0 += 32) {
        float av[8];
        if (k0 < Ksplit) Ld<TA >::load8(A  + (size_t)(m0 + ar) * HIDn + k0 + ac, av);
        else             Ld<TA2>::load8(A2 + (size_t)(m0 + ar) * HIDn + (k0 - Ksplit) + ac, av);
        #pragma unroll
        for (int t = 0; t < 8; ++t) As[ar][ac + t] = av[t];

        float bv[8];
        Ld<TW>::load8(W + (size_t)(k0 + br) * HIDn + n0 + bc, bv);
        #pragma unroll
        for (int t = 0; t < 8; ++t) Bs[br][bc + t] = bv[t];

        __syncthreads();
        #pragma unroll
        for (int k = 0; k < 32; ++k) {
            float a[4], b[4];
            #pragma unroll
            for (int i = 0; i < 4; ++i) a[i] = As[ty + 16 * i][k];
            #pragma unroll
            for (int j = 0; j < 4; ++j) b[j] = Bs[k][tx + 16 * j];
            #pragma unroll
            for (int i = 0; i < 4; ++i)
                #pragma unroll
                for (int j = 0; j < 4; ++j)
                    acc[i][j] += a[i] * b[j];
        }
        __syncthreads();
    }

    #pragma unroll
    for (int i = 0; i < 4; ++i) {
        const int row = m0 + ty + 16 * i;
        #pragma unroll
        for (int j = 0; j < 4; ++j) {
            const int col = n0 + tx + 16 * j;
            float v = acc[i][j] + Ld<TW>::ld1(bias + col);
            if (gate) {
                float g = bf2f(gate[(size_t)row * HIDn + col]);
                v = v / (1.f + expf(-g));
            }
            const size_t idx = (size_t)row * HIDn + col;
            if (c_fp32) ((float*)Cv)[idx] = v;
            else        ((unsigned short*)Cv)[idx] = f2bf(v);
        }
    }
}

// ---------------------------------------------------------------------------
// MFMA flash-style attention.
// Block = 64 q-rows of one (b,h); 4 waves x 16 rows. Two passes over K tiles:
//   pass1: QK^T via mfma_f32_16x16x32_bf16, online (m,l) per row (no storage)
//   pass2: recompute QK^T, p = exp(s-m)/l, write P (fp32/bf16 per flag),
//          P->LDS(bf16) re-layout, PV via MFMA vs LDS-transposed V tile.
// LDS row strides are odd multiples of 16B -> ds_read_b128 frags are <=2-way
// bank conflicts (free). K/V per head = 128KB each -> re-reads are L2/L3 hits.
// ---------------------------------------------------------------------------
#define QB 64
#define KT 128
#define KSTRIDE 72   // Qs/Ks row stride in ushort (144B = 9*16B)
#define VSTRIDE 136  // Vt/Ps row stride in ushort (272B = 17*16B)

__launch_bounds__(256, 2)
__global__ void attn_mfma_kernel(const unsigned short* __restrict__ Q,
                                 const unsigned short* __restrict__ Kb,
                                 const unsigned short* __restrict__ V,
                                 const int* __restrict__ mask,
                                 void* __restrict__ dout,
                                 unsigned short* __restrict__ xout,
                                 const int* __restrict__ flag)
{
    __shared__ __align__(16) unsigned short Qs[QB][KSTRIDE];   //  9216 B
    __shared__ __align__(16) unsigned short Ks[KT][KSTRIDE];   // 18432 B
    __shared__ __align__(16) unsigned short Vt[HDn][VSTRIDE];  // 17408 B  (V transposed: [d][key])
    __shared__ __align__(16) unsigned short Ps[QB][VSTRIDE];   // 17408 B  (bf16 P tile, per-wave bands)
    __shared__ float maskadd[KT];                              // total ~63 KB -> 2 blocks/CU

    const int bid = blockIdx.x;            // (b*NH + h)*(S/QB) + qb
    const int qb  = bid & 15;              // S/QB = 16
    const int h   = (bid >> 4) % NHn;
    const int b   = (bid >> 4) / NHn;
    const int q0  = qb * QB;

    const int tid  = threadIdx.x;
    const int lane = tid & 63;
    const int wid  = tid >> 6;             // wave id 0..3, owns q rows [wid*16, wid*16+16)
    const int l15  = lane & 15;
    const int g    = lane >> 4;            // 0..3
    const int ofp32 = *flag;

    // ---- stage Q tile [64][64] bf16 ----
    #pragma unroll
    for (int i = 0; i < 2; ++i) {
        const int chunk = i * 256 + tid;   // 0..511
        const int row = chunk >> 3;        // 0..63
        const int c8  = (chunk & 7) * 8;
        uint4 v = *(const uint4*)(Q + ((size_t)(b * Sn + q0 + row)) * HIDn + h * HDn + c8);
        *(uint4*)&Qs[row][c8] = v;
    }
    __syncthreads();

    // per-wave Q A-frags held in registers for the whole kernel.
    // A-frag layout (16x16x32): lane holds A[l&15][(l>>4)*8 + t], t=0..7 contiguous.
    short8 qa[2];
    #pragma unroll
    for (int ks = 0; ks < 2; ++ks)
        qa[ks] = *(const short8*)&Qs[wid * 16 + l15][ks * 32 + g * 8];

    // D-frag layout: row = (l>>4)*4 + r, col = l&15 (verified m89/m91).
    float mrow[4], lrow[4];
    #pragma unroll
    for (int r = 0; r < 4; ++r) { mrow[r] = -3.0e38f; lrow[r] = 0.f; }

    // ================= pass 1: online (m,l) =================
    #pragma unroll 1
    for (int kt = 0; kt < Sn; kt += KT) {
        __syncthreads();
        #pragma unroll
        for (int i = 0; i < 4; ++i) {
            const int chunk = i * 256 + tid;  // 0..1023
            const int row = chunk >> 3;       // 0..127
            const int c8  = (chunk & 7) * 8;
            uint4 v = *(const uint4*)(Kb + ((size_t)(b * Sn + kt + row)) * HIDn + h * HDn + c8);
            *(uint4*)&Ks[row][c8] = v;
        }
        if (tid < KT) maskadd[tid] = (mask[b * Sn + kt + tid] == 0) ? -1e10f : 0.0f;
        __syncthreads();

        f32x4 sacc[8];
        #pragma unroll
        for (int nt = 0; nt < 8; ++nt) sacc[nt] = (f32x4){0.f, 0.f, 0.f, 0.f};
        #pragma unroll
        for (int ks = 0; ks < 2; ++ks) {
            #pragma unroll
            for (int nt = 0; nt < 8; ++nt) {
                short8 kb = *(const short8*)&Ks[nt * 16 + l15][ks * 32 + g * 8];
                sacc[nt] = __builtin_amdgcn_mfma_f32_16x16x32_bf16(qa[ks], kb, sacc[nt], 0, 0, 0);
            }
        }
        #pragma unroll
        for (int r = 0; r < 4; ++r) {
            float sv[8], tmax = -3.0e38f;
            #pragma unroll
            for (int nt = 0; nt < 8; ++nt) {
                sv[nt] = sacc[nt][r] * 0.125f + maskadd[nt * 16 + l15];
                tmax = fmaxf(tmax, sv[nt]);
            }
            const float mnew = fmaxf(mrow[r], tmax);
            float acc = lrow[r] * __expf(mrow[r] - mnew);
            #pragma unroll
            for (int nt = 0; nt < 8; ++nt) acc += __expf(sv[nt] - mnew);
            lrow[r] = acc; mrow[r] = mnew;
        }
    }

    // cross-lane combine over the 16 lanes sharing each row (same l>>4 group).
    #pragma unroll
    for (int r = 0; r < 4; ++r) {
        float m = mrow[r], l = lrow[r];
        #pragma unroll
        for (int off = 1; off < 16; off <<= 1) {
            const float m2 = __shfl_xor(m, off);
            const float l2 = __shfl_xor(l, off);
            const float mn = fmaxf(m, m2);
            l = l * __expf(m - mn) + l2 * __expf(m2 - mn);
            m = mn;
        }
        mrow[r] = m;
        lrow[r] = 1.0f / l;   // lrow now holds 1/denominator
    }

    // ================= pass 2: P write + PV =================
    f32x4 xacc[4];
    #pragma unroll
    for (int dt = 0; dt < 4; ++dt) xacc[dt] = (f32x4){0.f, 0.f, 0.f, 0.f};

    #pragma unroll 1
    for (int kt = 0; kt < Sn; kt += KT) {
        __syncthreads();
        // K tile
        #pragma unroll
        for (int i = 0; i < 4; ++i) {
            const int chunk = i * 256 + tid;
            const int row = chunk >> 3;
            const int c8  = (chunk & 7) * 8;
            uint4 v = *(const uint4*)(Kb + ((size_t)(b * Sn + kt + row)) * HIDn + h * HDn + c8);
            *(uint4*)&Ks[row][c8] = v;
        }
        // V tile, transposed into Vt[d][key]
        #pragma unroll
        for (int i = 0; i < 4; ++i) {
            const int task = i * 256 + tid;   // 0..1023
            const int key = task >> 3;        // 0..127
            const int dg  = (task & 7) * 8;   // 0..56
            uint4 v = *(const uint4*)(V + ((size_t)(b * Sn + kt + key)) * HIDn + h * HDn + dg);
            const unsigned short* us = (const unsigned short*)&v;
            #pragma unroll
            for (int t = 0; t < 8; ++t) Vt[dg + t][key] = us[t];
        }
        if (tid < KT) maskadd[tid] = (mask[b * Sn + kt + tid] == 0) ? -1e10f : 0.0f;
        __syncthreads();

        // recompute QK^T for this tile
        f32x4 sacc[8];
        #pragma unroll
        for (int nt = 0; nt < 8; ++nt) sacc[nt] = (f32x4){0.f, 0.f, 0.f, 0.f};
        #pragma unroll
        for (int ks = 0; ks < 2; ++ks) {
            #pragma unroll
            for (int nt = 0; nt < 8; ++nt) {
                short8 kb = *(const short8*)&Ks[nt * 16 + l15][ks * 32 + g * 8];
                sacc[nt] = __builtin_amdgcn_mfma_f32_16x16x32_bf16(qa[ks], kb, sacc[nt], 0, 0, 0);
            }
        }

        // normalize, write attention output, stash bf16 P into this wave's Ps band
        const size_t arowbase =
            OUT0 + (((size_t)(b * NHn + h)) * Sn + (size_t)(q0 + wid * 16)) * (size_t)Sn;
        #pragma unroll
        for (int r = 0; r < 4; ++r) {
            const int rloc = g * 4 + r;
            #pragma unroll
            for (int nt = 0; nt < 8; ++nt) {
                const int col = nt * 16 + l15;
                const float sv = sacc[nt][r] * 0.125f + maskadd[col];
                const float p  = __expf(sv - mrow[r]) * lrow[r];
                const size_t oidx = arowbase + (size_t)rloc * Sn + kt + col;
                if (ofp32) __builtin_nontemporal_store(p, (float*)dout + oidx);
                else       __builtin_nontemporal_store(f2bf(p), (unsigned short*)dout + oidx);
                Ps[wid * 16 + rloc][col] = f2bf(p);
            }
        }
        // PV: A = P (from own-wave Ps band), B = V via Vt. Wave-private RAW on
        // Ps is ordered by lgkmcnt (compiler-inserted) — no cross-wave barrier.
        short8 pa[4];
        #pragma unroll
        for (int k2 = 0; k2 < 4; ++k2)
            pa[k2] = *(const short8*)&Ps[wid * 16 + l15][k2 * 32 + g * 8];
        #pragma unroll
        for (int dt = 0; dt < 4; ++dt) {
            #pragma unroll
            for (int k2 = 0; k2 < 4; ++k2) {
                short8 vb = *(const short8*)&Vt[dt * 16 + l15][k2 * 32 + g * 8];
                xacc[dt] = __builtin_amdgcn_mfma_f32_16x16x32_bf16(pa[k2], vb, xacc[dt], 0, 0, 0);
            }
        }
    }

    // ---- epilogue: X rows (bf16) to Xa in [B,S,NH*HD] layout ----
    #pragma unroll
    for (int dt = 0; dt < 4; ++dt) {
        #pragma unroll
        for (int r = 0; r < 4; ++r) {
            const int rloc = g * 4 + r;
            const int q = q0 + wid * 16 + rloc;
            const int d = dt * 16 + l15;
            xout[((size_t)(b * Sn + q)) * HIDn + h * HDn + d] = f2bf(xacc[dt][r]);
        }
    }
}

extern "C" void kernel_launch(void* const* d_in, const int* in_sizes, int n_in,
                              void* d_out, int out_size, void* d_ws, size_t ws_size,
                              hipStream_t stream)
{
    const int* mask = (const int*)d_in[3];

    char* ws = (char*)d_ws;
    const size_t SZ = (size_t)MROWS * HIDn * 2;  // 12.58 MB per bf16 [8192,768]
    unsigned short* Qb = (unsigned short*)(ws);
    unsigned short* Kb = (unsigned short*)(ws + SZ);
    unsigned short* Vb = (unsigned short*)(ws + 2 * SZ);
    unsigned short* Xa = (unsigned short*)(ws + 3 * SZ);
    int* flag = (int*)(ws + 4 * SZ);
    unsigned short* Yb = Qb;   // dead after attn
    unsigned short* H1 = Kb;   // dead after attn

    probe_kernel<<<1, 256, 0, stream>>>((const unsigned short*)d_in[0], flag);

    dim3 gg(HIDn / 64, MROWS / 64);  // (12, 128)
    const int BIG = 1 << 30;

    // ---------- QKV projections ----------
    {   // mode 0: bf16 inputs
        typedef unsigned short T;
        gemm_kernel<T,T,T><<<gg,256,0,stream>>>((const T*)d_in[0],(const T*)d_in[0],BIG,HIDn,
            (const T*)d_in[4],(const T*)d_in[5],nullptr,Qb,0,flag,0);
        gemm_kernel<T,T,T><<<gg,256,0,stream>>>((const T*)d_in[1],(const T*)d_in[1],BIG,HIDn,
            (const T*)d_in[6],(const T*)d_in[7],nullptr,Kb,0,flag,0);
        gemm_kernel<T,T,T><<<gg,256,0,stream>>>((const T*)d_in[2],(const T*)d_in[2],BIG,HIDn,
            (const T*)d_in[8],(const T*)d_in[9],nullptr,Vb,0,flag,0);
    }
    {   // mode 1: fp32 inputs
        typedef float T;
        gemm_kernel<T,T,T><<<gg,256,0,stream>>>((const T*)d_in[0],(const T*)d_in[0],BIG,HIDn,
            (const T*)d_in[4],(const T*)d_in[5],nullptr,Qb,0,flag,1);
        gemm_kernel<T,T,T><<<gg,256,0,stream>>>((const T*)d_in[1],(const T*)d_in[1],BIG,HIDn,
            (const T*)d_in[6],(const T*)d_in[7],nullptr,Kb,0,flag,1);
        gemm_kernel<T,T,T><<<gg,256,0,stream>>>((const T*)d_in[2],(const T*)d_in[2],BIG,HIDn,
            (const T*)d_in[8],(const T*)d_in[9],nullptr,Vb,0,flag,1);
    }

    // ---------- attention (MFMA, out1 dtype switched on flag inside) ----------
    attn_mfma_kernel<<<Bn * NHn * (Sn / QB), 256, 0, stream>>>(Qb, Kb, Vb, mask, d_out, Xa, flag);

    // ---------- Wo projection + FFN ----------
    {   // mode 0
        typedef unsigned short T;
        gemm_kernel<T,T,T><<<gg,256,0,stream>>>(Xa,Xa,BIG,HIDn,
            (const T*)d_in[10],(const T*)d_in[11],nullptr,Yb,0,flag,0);
        gemm_kernel<T,T,T><<<gg,256,0,stream>>>(Yb,(const T*)d_in[0],HIDn,2*HIDn,
            (const T*)d_in[12],(const T*)d_in[13],nullptr,H1,0,flag,0);
        gemm_kernel<T,T,T><<<gg,256,0,stream>>>(Yb,(const T*)d_in[0],HIDn,2*HIDn,
            (const T*)d_in[14],(const T*)d_in[15],H1,d_out,/*c_fp32=*/0,flag,0);
    }
    {   // mode 1
        typedef float T;
        gemm_kernel<unsigned short,unsigned short,T><<<gg,256,0,stream>>>(Xa,Xa,BIG,HIDn,
            (const T*)d_in[10],(const T*)d_in[11],nullptr,Yb,0,flag,1);
        gemm_kernel<unsigned short,T,T><<<gg,256,0,stream>>>(Yb,(const T*)d_in[0],HIDn,2*HIDn,
            (const T*)d_in[12],(const T*)d_in[13],nullptr,H1,0,flag,1);
        gemm_kernel<unsigned short,T,T><<<gg,256,0,stream>>>(Yb,(const T*)d_in[0],HIDn,2*HIDn,
            (const T*)d_in[14],(const T*)d_in[15],H1,d_out,/*c_fp32=*/1,flag,1);
    }
}

// Round 2
// 1009.898 us; speedup vs baseline: 5.9186x; 1.8976x over previous
//
#include <hip/hip_runtime.h>
#include <hip/hip_bf16.h>

#define Bn   8
#define Sn   1024
#define HIDn 768
#define NHn  12
#define HDn  64
#define MROWS (Bn * Sn)              // 8192
#define OUT0  ((size_t)MROWS * HIDn) // 6291456

typedef __attribute__((ext_vector_type(8))) short short8;
typedef __attribute__((ext_vector_type(4))) float f32x4;

__device__ __forceinline__ float bf2f(unsigned short u) {
    union { unsigned int i; float f; } v;
    v.i = ((unsigned int)u) << 16;
    return v.f;
}
__device__ __forceinline__ unsigned short f2bf(float f) {
    __hip_bfloat16 h = __float2bfloat16(f);
    return *reinterpret_cast<unsigned short*>(&h);
}

template <typename T> struct IsFP32              { static constexpr bool v = false; };
template <>           struct IsFP32<float>       { static constexpr bool v = true;  };

__device__ __forceinline__ float ld1f(const unsigned short* p) { return bf2f(*p); }
__device__ __forceinline__ float ld1f(const float* p)          { return *p; }

// contiguous 8-elem load -> hi/lo bf16 split (lo = bf16(x - bf16(x)))
__device__ __forceinline__ void load8s(const unsigned short* p, short8& h, short8& l) {
    h = *(const short8*)p;
    #pragma unroll
    for (int t = 0; t < 8; ++t) l[t] = 0;
}
__device__ __forceinline__ void load8s(const float* p, short8& h, short8& l) {
    float4 a = *(const float4*)p;
    float4 b = *(const float4*)(p + 4);
    float f[8] = {a.x, a.y, a.z, a.w, b.x, b.y, b.z, b.w};
    #pragma unroll
    for (int t = 0; t < 8; ++t) {
        unsigned short hu = f2bf(f[t]);
        h[t] = (short)hu;
        l[t] = (short)f2bf(f[t] - bf2f(hu));
    }
}
// strided (k-contiguous) 8-elem load -> hi/lo split
__device__ __forceinline__ void load8k(const unsigned short* p, int stride, short8& h, short8& l) {
    #pragma unroll
    for (int t = 0; t < 8; ++t) { h[t] = (short)p[(size_t)t * stride]; l[t] = 0; }
}
__device__ __forceinline__ void load8k(const float* p, int stride, short8& h, short8& l) {
    #pragma unroll
    for (int t = 0; t < 8; ++t) {
        float f = p[(size_t)t * stride];
        unsigned short hu = f2bf(f);
        h[t] = (short)hu;
        l[t] = (short)f2bf(f - bf2f(hu));
    }
}

// dtype probe: even-index ushorts of fp32 data are random low-mantissa bits
// (~45% insane as bf16); of bf16 data they are sane values. flag: 1=fp32, 0=bf16.
__global__ void probe_kernel(const unsigned short* __restrict__ q, int* __restrict__ flag) {
    __shared__ int cnt;
    if (threadIdx.x == 0) cnt = 0;
    __syncthreads();
    int ins = 0;
    for (int i = threadIdx.x; i < 4096; i += 256) {
        unsigned short u = q[2 * i];
        int e = (u >> 7) & 0xFF;
        float v = bf2f(u);
        if (e == 0xFF || fabsf(v) > 1e4f) ins++;
    }
    atomicAdd(&cnt, ins);
    __syncthreads();
    if (threadIdx.x == 0) *flag = (cnt > 400) ? 1 : 0;
}

// ---------------------------------------------------------------------------
// MFMA GEMM with split-precision (hi+lo bf16) for fp32 operands:
//   C = A_cat @ W + bias  [+ sigmoid-gate epilogue]
// acc = ahi*bhi + ahi*blo + alo*bhi  (alo*blo ~2^-18 rel, dropped)
// BM=128, BN=64, BK=32; 4 waves as 2x2; per-wave 64x32 via 16x16x32 MFMA.
// LDS row stride 40 ushorts = 80B = 5*16B (odd multiple) -> <=2-way conflicts
// on all b128 frag reads (free per m136). B staged transposed [n][k] via
// k-contiguous global loads so LDS writes stay b128-vectorized.
// ---------------------------------------------------------------------------
template <typename TA, typename TA2, typename TW>
__launch_bounds__(256, 2)
__global__ void gemm_mfma(const TA*  __restrict__ A,
                          const TA2* __restrict__ A2,
                          int Ksplit, int K,
                          const TW* __restrict__ W,
                          const TW* __restrict__ bias,
                          const unsigned short* __restrict__ gate,
                          void* __restrict__ Cv, int c_fp32,
                          const int* __restrict__ flag, int mymode)
{
    if (*flag != mymode) return;

    constexpr bool AFP  = IsFP32<TA>::v;
    constexpr bool A2FP = IsFP32<TA2>::v;
    constexpr bool WFP  = IsFP32<TW>::v;

    __shared__ __align__(16) unsigned short Ash[128][40];
    __shared__ __align__(16) unsigned short Asl[128][40];
    __shared__ __align__(16) unsigned short Bth[64][40];
    __shared__ __align__(16) unsigned short Btl[64][40];

    const int tid  = threadIdx.x;
    const int lane = tid & 63;
    const int wid  = tid >> 6;
    const int wr   = wid >> 1;       // 0..1 -> M half (64 rows)
    const int wc   = wid & 1;        // 0..1 -> N half (32 cols)
    const int l15  = lane & 15;
    const int g    = lane >> 4;      // 0..3
    const int n0   = blockIdx.x * 64;
    const int m0   = blockIdx.y * 128;

    f32x4 acc[4][2];
    #pragma unroll
    for (int mi = 0; mi < 4; ++mi)
        #pragma unroll
        for (int ni = 0; ni < 2; ++ni)
            acc[mi][ni] = (f32x4){0.f, 0.f, 0.f, 0.f};

    for (int k0 = 0; k0 < K; k0 += 32) {
        const bool fromA = (k0 < Ksplit);
        const bool allo  = fromA ? AFP : A2FP;   // block-uniform

        // ---- stage A tile [128][32] (hi + optional lo) ----
        #pragma unroll
        for (int t = 0; t < 2; ++t) {
            const int idx = t * 256 + tid;   // 0..511
            const int row = idx >> 2;        // 0..127
            const int c8  = (idx & 3) * 8;   // 0,8,16,24
            short8 h, l;
            if (fromA) load8s(A  + (size_t)(m0 + row) * HIDn + k0 + c8, h, l);
            else       load8s(A2 + (size_t)(m0 + row) * HIDn + (k0 - Ksplit) + c8, h, l);
            *(short8*)&Ash[row][c8] = h;
            if (allo) *(short8*)&Asl[row][c8] = l;
        }
        // ---- stage B transposed [n][k], 64x32 ----
        {
            const int nn = tid >> 2;         // 0..63
            const int kg = (tid & 3) * 8;    // 0,8,16,24
            short8 h, l;
            load8k(W + (size_t)(k0 + kg) * HIDn + n0 + nn, HIDn, h, l);
            *(short8*)&Bth[nn][kg] = h;
            if (WFP) *(short8*)&Btl[nn][kg] = l;
        }
        __syncthreads();

        // ---- frag loads ----
        short8 ah[4], bh[2], al[4], bl[2];
        #pragma unroll
        for (int mi = 0; mi < 4; ++mi)
            ah[mi] = *(const short8*)&Ash[wr * 64 + mi * 16 + l15][g * 8];
        #pragma unroll
        for (int ni = 0; ni < 2; ++ni)
            bh[ni] = *(const short8*)&Bth[wc * 32 + ni * 16 + l15][g * 8];
        if (allo) {
            #pragma unroll
            for (int mi = 0; mi < 4; ++mi)
                al[mi] = *(const short8*)&Asl[wr * 64 + mi * 16 + l15][g * 8];
        }
        if (WFP) {
            #pragma unroll
            for (int ni = 0; ni < 2; ++ni)
                bl[ni] = *(const short8*)&Btl[wc * 32 + ni * 16 + l15][g * 8];
        }

        // ---- MFMA: hi*hi always; cross terms when split ----
        #pragma unroll
        for (int mi = 0; mi < 4; ++mi)
            #pragma unroll
            for (int ni = 0; ni < 2; ++ni)
                acc[mi][ni] = __builtin_amdgcn_mfma_f32_16x16x32_bf16(ah[mi], bh[ni], acc[mi][ni], 0, 0, 0);
        if (WFP) {
            #pragma unroll
            for (int mi = 0; mi < 4; ++mi)
                #pragma unroll
                for (int ni = 0; ni < 2; ++ni)
                    acc[mi][ni] = __builtin_amdgcn_mfma_f32_16x16x32_bf16(ah[mi], bl[ni], acc[mi][ni], 0, 0, 0);
        }
        if (allo) {
            #pragma unroll
            for (int mi = 0; mi < 4; ++mi)
                #pragma unroll
                for (int ni = 0; ni < 2; ++ni)
                    acc[mi][ni] = __builtin_amdgcn_mfma_f32_16x16x32_bf16(al[mi], bh[ni], acc[mi][ni], 0, 0, 0);
        }
        __syncthreads();
    }

    // ---- epilogue: D row = g*4+r, col = l15 (verified m89/m91) ----
    #pragma unroll
    for (int mi = 0; mi < 4; ++mi) {
        #pragma unroll
        for (int ni = 0; ni < 2; ++ni) {
            const int col = n0 + wc * 32 + ni * 16 + l15;
            const float bv = ld1f(bias + col);
            #pragma unroll
            for (int r = 0; r < 4; ++r) {
                const int row = m0 + wr * 64 + mi * 16 + g * 4 + r;
                float v = acc[mi][ni][r] + bv;
                if (gate) {
                    float gt = bf2f(gate[(size_t)row * HIDn + col]);
                    v = v / (1.f + expf(-gt));
                }
                const size_t idx = (size_t)row * HIDn + col;
                if (c_fp32) ((float*)Cv)[idx] = v;
                else        ((unsigned short*)Cv)[idx] = f2bf(v);
            }
        }
    }
}

// ---------------------------------------------------------------------------
// MFMA flash-style attention (round-1, verified). Block = 64 q-rows of one
// (b,h); 4 waves x 16 rows. Pass1 online (m,l); pass2 recompute + P write + PV.
// ---------------------------------------------------------------------------
#define QB 64
#define KT 128
#define KSTRIDE 72   // Qs/Ks row stride in ushort (144B = 9*16B)
#define VSTRIDE 136  // Vt/Ps row stride in ushort (272B = 17*16B)

__launch_bounds__(256, 2)
__global__ void attn_mfma_kernel(const unsigned short* __restrict__ Q,
                                 const unsigned short* __restrict__ Kb,
                                 const unsigned short* __restrict__ V,
                                 const int* __restrict__ mask,
                                 void* __restrict__ dout,
                                 unsigned short* __restrict__ xout,
                                 const int* __restrict__ flag)
{
    __shared__ __align__(16) unsigned short Qs[QB][KSTRIDE];
    __shared__ __align__(16) unsigned short Ks[KT][KSTRIDE];
    __shared__ __align__(16) unsigned short Vt[HDn][VSTRIDE];
    __shared__ __align__(16) unsigned short Ps[QB][VSTRIDE];
    __shared__ float maskadd[KT];

    const int bid = blockIdx.x;
    const int qb  = bid & 15;
    const int h   = (bid >> 4) % NHn;
    const int b   = (bid >> 4) / NHn;
    const int q0  = qb * QB;

    const int tid  = threadIdx.x;
    const int lane = tid & 63;
    const int wid  = tid >> 6;
    const int l15  = lane & 15;
    const int g    = lane >> 4;
    const int ofp32 = *flag;

    #pragma unroll
    for (int i = 0; i < 2; ++i) {
        const int chunk = i * 256 + tid;
        const int row = chunk >> 3;
        const int c8  = (chunk & 7) * 8;
        uint4 v = *(const uint4*)(Q + ((size_t)(b * Sn + q0 + row)) * HIDn + h * HDn + c8);
        *(uint4*)&Qs[row][c8] = v;
    }
    __syncthreads();

    short8 qa[2];
    #pragma unroll
    for (int ks = 0; ks < 2; ++ks)
        qa[ks] = *(const short8*)&Qs[wid * 16 + l15][ks * 32 + g * 8];

    float mrow[4], lrow[4];
    #pragma unroll
    for (int r = 0; r < 4; ++r) { mrow[r] = -3.0e38f; lrow[r] = 0.f; }

    // ================= pass 1: online (m,l) =================
    #pragma unroll 1
    for (int kt = 0; kt < Sn; kt += KT) {
        __syncthreads();
        #pragma unroll
        for (int i = 0; i < 4; ++i) {
            const int chunk = i * 256 + tid;
            const int row = chunk >> 3;
            const int c8  = (chunk & 7) * 8;
            uint4 v = *(const uint4*)(Kb + ((size_t)(b * Sn + kt + row)) * HIDn + h * HDn + c8);
            *(uint4*)&Ks[row][c8] = v;
        }
        if (tid < KT) maskadd[tid] = (mask[b * Sn + kt + tid] == 0) ? -1e10f : 0.0f;
        __syncthreads();

        f32x4 sacc[8];
        #pragma unroll
        for (int nt = 0; nt < 8; ++nt) sacc[nt] = (f32x4){0.f, 0.f, 0.f, 0.f};
        #pragma unroll
        for (int ks = 0; ks < 2; ++ks) {
            #pragma unroll
            for (int nt = 0; nt < 8; ++nt) {
                short8 kb = *(const short8*)&Ks[nt * 16 + l15][ks * 32 + g * 8];
                sacc[nt] = __builtin_amdgcn_mfma_f32_16x16x32_bf16(qa[ks], kb, sacc[nt], 0, 0, 0);
            }
        }
        #pragma unroll
        for (int r = 0; r < 4; ++r) {
            float sv[8], tmax = -3.0e38f;
            #pragma unroll
            for (int nt = 0; nt < 8; ++nt) {
                sv[nt] = sacc[nt][r] * 0.125f + maskadd[nt * 16 + l15];
                tmax = fmaxf(tmax, sv[nt]);
            }
            const float mnew = fmaxf(mrow[r], tmax);
            float acc = lrow[r] * __expf(mrow[r] - mnew);
            #pragma unroll
            for (int nt = 0; nt < 8; ++nt) acc += __expf(sv[nt] - mnew);
            lrow[r] = acc; mrow[r] = mnew;
        }
    }

    #pragma unroll
    for (int r = 0; r < 4; ++r) {
        float m = mrow[r], l = lrow[r];
        #pragma unroll
        for (int off = 1; off < 16; off <<= 1) {
            const float m2 = __shfl_xor(m, off);
            const float l2 = __shfl_xor(l, off);
            const float mn = fmaxf(m, m2);
            l = l * __expf(m - mn) + l2 * __expf(m2 - mn);
            m = mn;
        }
        mrow[r] = m;
        lrow[r] = 1.0f / l;
    }

    // ================= pass 2: P write + PV =================
    f32x4 xacc[4];
    #pragma unroll
    for (int dt = 0; dt < 4; ++dt) xacc[dt] = (f32x4){0.f, 0.f, 0.f, 0.f};

    #pragma unroll 1
    for (int kt = 0; kt < Sn; kt += KT) {
        __syncthreads();
        #pragma unroll
        for (int i = 0; i < 4; ++i) {
            const int chunk = i * 256 + tid;
            const int row = chunk >> 3;
            const int c8  = (chunk & 7) * 8;
            uint4 v = *(const uint4*)(Kb + ((size_t)(b * Sn + kt + row)) * HIDn + h * HDn + c8);
            *(uint4*)&Ks[row][c8] = v;
        }
        #pragma unroll
        for (int i = 0; i < 4; ++i) {
            const int task = i * 256 + tid;
            const int key = task >> 3;
            const int dg  = (task & 7) * 8;
            uint4 v = *(const uint4*)(V + ((size_t)(b * Sn + kt + key)) * HIDn + h * HDn + dg);
            const unsigned short* us = (const unsigned short*)&v;
            #pragma unroll
            for (int t = 0; t < 8; ++t) Vt[dg + t][key] = us[t];
        }
        if (tid < KT) maskadd[tid] = (mask[b * Sn + kt + tid] == 0) ? -1e10f : 0.0f;
        __syncthreads();

        f32x4 sacc[8];
        #pragma unroll
        for (int nt = 0; nt < 8; ++nt) sacc[nt] = (f32x4){0.f, 0.f, 0.f, 0.f};
        #pragma unroll
        for (int ks = 0; ks < 2; ++ks) {
            #pragma unroll
            for (int nt = 0; nt < 8; ++nt) {
                short8 kb = *(const short8*)&Ks[nt * 16 + l15][ks * 32 + g * 8];
                sacc[nt] = __builtin_amdgcn_mfma_f32_16x16x32_bf16(qa[ks], kb, sacc[nt], 0, 0, 0);
            }
        }

        const size_t arowbase =
            OUT0 + (((size_t)(b * NHn + h)) * Sn + (size_t)(q0 + wid * 16)) * (size_t)Sn;
        #pragma unroll
        for (int r = 0; r < 4; ++r) {
            const int rloc = g * 4 + r;
            #pragma unroll
            for (int nt = 0; nt < 8; ++nt) {
                const int col = nt * 16 + l15;
                const float sv = sacc[nt][r] * 0.125f + maskadd[col];
                const float p  = __expf(sv - mrow[r]) * lrow[r];
                const size_t oidx = arowbase + (size_t)rloc * Sn + kt + col;
                if (ofp32) __builtin_nontemporal_store(p, (float*)dout + oidx);
                else       __builtin_nontemporal_store(f2bf(p), (unsigned short*)dout + oidx);
                Ps[wid * 16 + rloc][col] = f2bf(p);
            }
        }
        short8 pa[4];
        #pragma unroll
        for (int k2 = 0; k2 < 4; ++k2)
            pa[k2] = *(const short8*)&Ps[wid * 16 + l15][k2 * 32 + g * 8];
        #pragma unroll
        for (int dt = 0; dt < 4; ++dt) {
            #pragma unroll
            for (int k2 = 0; k2 < 4; ++k2) {
                short8 vb = *(const short8*)&Vt[dt * 16 + l15][k2 * 32 + g * 8];
                xacc[dt] = __builtin_amdgcn_mfma_f32_16x16x32_bf16(pa[k2], vb, xacc[dt], 0, 0, 0);
            }
        }
    }

    #pragma unroll
    for (int dt = 0; dt < 4; ++dt) {
        #pragma unroll
        for (int r = 0; r < 4; ++r) {
            const int rloc = g * 4 + r;
            const int q = q0 + wid * 16 + rloc;
            const int d = dt * 16 + l15;
            xout[((size_t)(b * Sn + q)) * HIDn + h * HDn + d] = f2bf(xacc[dt][r]);
        }
    }
}

extern "C" void kernel_launch(void* const* d_in, const int* in_sizes, int n_in,
                              void* d_out, int out_size, void* d_ws, size_t ws_size,
                              hipStream_t stream)
{
    const int* mask = (const int*)d_in[3];

    char* ws = (char*)d_ws;
    const size_t SZ = (size_t)MROWS * HIDn * 2;  // 12.58 MB per bf16 [8192,768]
    unsigned short* Qb = (unsigned short*)(ws);
    unsigned short* Kb = (unsigned short*)(ws + SZ);
    unsigned short* Vb = (unsigned short*)(ws + 2 * SZ);
    unsigned short* Xa = (unsigned short*)(ws + 3 * SZ);
    int* flag = (int*)(ws + 4 * SZ);
    unsigned short* Yb = Qb;   // dead after attn
    unsigned short* H1 = Kb;   // dead after attn

    probe_kernel<<<1, 256, 0, stream>>>((const unsigned short*)d_in[0], flag);

    dim3 gg(HIDn / 64, MROWS / 128);  // (12, 64) -> 768 blocks = 3/CU exact
    const int BIG = 1 << 30;

    // ---------- QKV projections ----------
    {   // mode 0: bf16 inputs
        typedef unsigned short T;
        gemm_mfma<T,T,T><<<gg,256,0,stream>>>((const T*)d_in[0],(const T*)d_in[0],BIG,HIDn,
            (const T*)d_in[4],(const T*)d_in[5],nullptr,Qb,0,flag,0);
        gemm_mfma<T,T,T><<<gg,256,0,stream>>>((const T*)d_in[1],(const T*)d_in[1],BIG,HIDn,
            (const T*)d_in[6],(const T*)d_in[7],nullptr,Kb,0,flag,0);
        gemm_mfma<T,T,T><<<gg,256,0,stream>>>((const T*)d_in[2],(const T*)d_in[2],BIG,HIDn,
            (const T*)d_in[8],(const T*)d_in[9],nullptr,Vb,0,flag,0);
    }
    {   // mode 1: fp32 inputs (split-precision)
        typedef float T;
        gemm_mfma<T,T,T><<<gg,256,0,stream>>>((const T*)d_in[0],(const T*)d_in[0],BIG,HIDn,
            (const T*)d_in[4],(const T*)d_in[5],nullptr,Qb,0,flag,1);
        gemm_mfma<T,T,T><<<gg,256,0,stream>>>((const T*)d_in[1],(const T*)d_in[1],BIG,HIDn,
            (const T*)d_in[6],(const T*)d_in[7],nullptr,Kb,0,flag,1);
        gemm_mfma<T,T,T><<<gg,256,0,stream>>>((const T*)d_in[2],(const T*)d_in[2],BIG,HIDn,
            (const T*)d_in[8],(const T*)d_in[9],nullptr,Vb,0,flag,1);
    }

    // ---------- attention (MFMA, out1 dtype switched on flag inside) ----------
    attn_mfma_kernel<<<Bn * NHn * (Sn / QB), 256, 0, stream>>>(Qb, Kb, Vb, mask, d_out, Xa, flag);

    // ---------- Wo projection + FFN ----------
    {   // mode 0
        typedef unsigned short T;
        gemm_mfma<T,T,T><<<gg,256,0,stream>>>(Xa,Xa,BIG,HIDn,
            (const T*)d_in[10],(const T*)d_in[11],nullptr,Yb,0,flag,0);
        gemm_mfma<T,T,T><<<gg,256,0,stream>>>(Yb,(const T*)d_in[0],HIDn,2*HIDn,
            (const T*)d_in[12],(const T*)d_in[13],nullptr,H1,0,flag,0);
        gemm_mfma<T,T,T><<<gg,256,0,stream>>>(Yb,(const T*)d_in[0],HIDn,2*HIDn,
            (const T*)d_in[14],(const T*)d_in[15],H1,d_out,/*c_fp32=*/0,flag,0);
    }
    {   // mode 1
        typedef float T;
        gemm_mfma<unsigned short,unsigned short,T><<<gg,256,0,stream>>>(Xa,Xa,BIG,HIDn,
            (const T*)d_in[10],(const T*)d_in[11],nullptr,Yb,0,flag,1);
        gemm_mfma<unsigned short,T,T><<<gg,256,0,stream>>>(Yb,(const T*)d_in[0],HIDn,2*HIDn,
            (const T*)d_in[12],(const T*)d_in[13],nullptr,H1,0,flag,1);
        gemm_mfma<unsigned short,T,T><<<gg,256,0,stream>>>(Yb,(const T*)d_in[0],HIDn,2*HIDn,
            (const T*)d_in[14],(const T*)d_in[15],H1,d_out,/*c_fp32=*/1,flag,1);
    }
}

// Round 5
// 969.159 us; speedup vs baseline: 6.1674x; 1.0420x over previous
//
#include <hip/hip_runtime.h>
#include <hip/hip_bf16.h>

#define Bn   8
#define Sn   1024
#define HIDn 768
#define NHn  12
#define HDn  64
#define MROWS (Bn * Sn)              // 8192
#define OUT0  ((size_t)MROWS * HIDn) // 6291456

typedef __attribute__((ext_vector_type(8))) short short8;
typedef __attribute__((ext_vector_type(4))) float f32x4;

__device__ __forceinline__ float bf2f(unsigned short u) {
    union { unsigned int i; float f; } v;
    v.i = ((unsigned int)u) << 16;
    return v.f;
}
__device__ __forceinline__ unsigned short f2bf(float f) {
    __hip_bfloat16 h = __float2bfloat16(f);
    return *reinterpret_cast<unsigned short*>(&h);
}

template <typename T> struct IsFP32              { static constexpr bool v = false; };
template <>           struct IsFP32<float>       { static constexpr bool v = true;  };

__device__ __forceinline__ float ld1f(const unsigned short* p) { return bf2f(*p); }
__device__ __forceinline__ float ld1f(const float* p)          { return *p; }

// contiguous 8-elem load -> hi/lo bf16 split (lo = bf16(x - bf16(x)))
__device__ __forceinline__ void load8s(const unsigned short* p, short8& h, short8& l) {
    h = *(const short8*)p;
    #pragma unroll
    for (int t = 0; t < 8; ++t) l[t] = 0;
}
__device__ __forceinline__ void load8s(const float* p, short8& h, short8& l) {
    float4 a = *(const float4*)p;
    float4 b = *(const float4*)(p + 4);
    float f[8] = {a.x, a.y, a.z, a.w, b.x, b.y, b.z, b.w};
    #pragma unroll
    for (int t = 0; t < 8; ++t) {
        unsigned short hu = f2bf(f[t]);
        h[t] = (short)hu;
        l[t] = (short)f2bf(f[t] - bf2f(hu));
    }
}

// dtype probe: even-index ushorts of fp32 data are random low-mantissa bits
// (~45% insane as bf16); of bf16 data they are sane values. flag: 1=fp32, 0=bf16.
__global__ void probe_kernel(const unsigned short* __restrict__ q, int* __restrict__ flag) {
    __shared__ int cnt;
    if (threadIdx.x == 0) cnt = 0;
    __syncthreads();
    int ins = 0;
    for (int i = threadIdx.x; i < 4096; i += 256) {
        unsigned short u = q[2 * i];
        int e = (u >> 7) & 0xFF;
        float v = bf2f(u);
        if (e == 0xFF || fabsf(v) > 1e4f) ins++;
    }
    atomicAdd(&cnt, ins);
    __syncthreads();
    if (threadIdx.x == 0) *flag = (cnt > 400) ? 1 : 0;
}

// ---------------------------------------------------------------------------
// One-shot weight prep: W [K][768] (fp32 or bf16 per flag) -> transposed
// bf16 hi/lo pair Wt_h/Wt_l [768][K]. Split arithmetic IDENTICAL to the
// round-2 in-kernel split (f2bf(f), f2bf(f - bf2f(hi))) -> GEMM LDS contents
// bit-exact vs round 2. bf16 input: hi = exact roundtrip, lo = +0 exactly.
// One launch handles up to 3 matrices via blockIdx.z; K per matrix.
// ---------------------------------------------------------------------------
__global__ void prep_w(const void* __restrict__ s0, const void* __restrict__ s1,
                       const void* __restrict__ s2,
                       unsigned short* __restrict__ d0h, unsigned short* __restrict__ d0l,
                       unsigned short* __restrict__ d1h, unsigned short* __restrict__ d1l,
                       unsigned short* __restrict__ d2h, unsigned short* __restrict__ d2l,
                       int K0, int K1, int K2, const int* __restrict__ flag)
{
    const int z = blockIdx.z;
    const void* src    = (z == 0) ? s0 : (z == 1) ? s1 : s2;
    unsigned short* dh = (z == 0) ? d0h : (z == 1) ? d1h : d2h;
    unsigned short* dl = (z == 0) ? d0l : (z == 1) ? d1l : d2l;
    const int K        = (z == 0) ? K0 : (z == 1) ? K1 : K2;

    const int k0 = blockIdx.x * 64;
    if (k0 >= K) return;
    const int n0 = blockIdx.y * 64;
    const bool fp32 = (*flag != 0);

    __shared__ float tile[64][65];
    const int tx = threadIdx.x & 15, ty = threadIdx.x >> 4;

    #pragma unroll
    for (int i = 0; i < 4; ++i) {
        const int k = ty + 16 * i;
        const size_t off = (size_t)(k0 + k) * HIDn + n0 + tx * 4;
        if (fp32) {
            float4 v = *(const float4*)((const float*)src + off);
            tile[k][tx * 4 + 0] = v.x; tile[k][tx * 4 + 1] = v.y;
            tile[k][tx * 4 + 2] = v.z; tile[k][tx * 4 + 3] = v.w;
        } else {
            ushort4 v = *(const ushort4*)((const unsigned short*)src + off);
            tile[k][tx * 4 + 0] = bf2f(v.x); tile[k][tx * 4 + 1] = bf2f(v.y);
            tile[k][tx * 4 + 2] = bf2f(v.z); tile[k][tx * 4 + 3] = bf2f(v.w);
        }
    }
    __syncthreads();

    #pragma unroll
    for (int i = 0; i < 4; ++i) {
        const int n  = ty + 16 * i;   // local n row of Wt
        const int kk = tx * 4;        // local k col group
        ushort4 hh, ll;
        float f0 = tile[kk + 0][n], f1 = tile[kk + 1][n];
        float f2 = tile[kk + 2][n], f3 = tile[kk + 3][n];
        hh.x = f2bf(f0); ll.x = f2bf(f0 - bf2f(hh.x));
        hh.y = f2bf(f1); ll.y = f2bf(f1 - bf2f(hh.y));
        hh.z = f2bf(f2); ll.z = f2bf(f2 - bf2f(hh.z));
        hh.w = f2bf(f3); ll.w = f2bf(f3 - bf2f(hh.w));
        const size_t off = (size_t)(n0 + n) * K + k0 + kk;
        *(ushort4*)(dh + off) = hh;
        *(ushort4*)(dl + off) = ll;
    }
}

// ---------------------------------------------------------------------------
// MFMA GEMM, split-precision (round-2-exact math):
//   acc = ahi*bhi [+ ahi*blo if WFP] [+ alo*bhi if A-side fp32]
// B loads from PRE-transposed/PRE-split Wt_h/Wt_l [768][K] bf16 buffers
// (prep_w) -> staging is two 16B copies; LDS contents bit-identical to round 2.
// BM=128, BN=64, BK=32; 4 waves 2x2; 16x16x32 MFMA. TW only selects bias
// dtype + whether the ahi*blo term runs (fp32-mode). Dual-launch per mode
// with early-return on flag mismatch (round-2-proven).
// ---------------------------------------------------------------------------
template <typename TA, typename TA2, typename TW>
__launch_bounds__(256, 2)
__global__ void gemm_mfma(const TA*  __restrict__ A,
                          const TA2* __restrict__ A2,
                          int Ksplit, int K,
                          const unsigned short* __restrict__ Wth,
                          const unsigned short* __restrict__ Wtl,
                          const TW* __restrict__ bias,
                          const unsigned short* __restrict__ gate,
                          void* __restrict__ Cv, int c_fp32,
                          const int* __restrict__ flag, int mymode)
{
    if (*flag != mymode) return;

    constexpr bool AFP  = IsFP32<TA>::v;
    constexpr bool A2FP = IsFP32<TA2>::v;
    constexpr bool WFP  = IsFP32<TW>::v;

    __shared__ __align__(16) unsigned short Ash[128][40];
    __shared__ __align__(16) unsigned short Asl[128][40];
    __shared__ __align__(16) unsigned short Bth[64][40];
    __shared__ __align__(16) unsigned short Btl[64][40];

    const int tid  = threadIdx.x;
    const int lane = tid & 63;
    const int wid  = tid >> 6;
    const int wr   = wid >> 1;       // M half (64 rows)
    const int wc   = wid & 1;        // N half (32 cols)
    const int l15  = lane & 15;
    const int g    = lane >> 4;      // 0..3
    const int n0   = blockIdx.x * 64;
    const int m0   = blockIdx.y * 128;

    f32x4 acc[4][2];
    #pragma unroll
    for (int mi = 0; mi < 4; ++mi)
        #pragma unroll
        for (int ni = 0; ni < 2; ++ni)
            acc[mi][ni] = (f32x4){0.f, 0.f, 0.f, 0.f};

    for (int k0 = 0; k0 < K; k0 += 32) {
        const bool fromA = (k0 < Ksplit);
        const bool alo   = fromA ? AFP : A2FP;   // block-uniform

        // ---- stage A tile [128][32] (hi + optional lo) ----
        #pragma unroll
        for (int t = 0; t < 2; ++t) {
            const int idx = t * 256 + tid;   // 0..511
            const int row = idx >> 2;        // 0..127
            const int c8  = (idx & 3) * 8;   // 0,8,16,24
            short8 h, l;
            if (fromA) load8s(A  + (size_t)(m0 + row) * HIDn + k0 + c8, h, l);
            else       load8s(A2 + (size_t)(m0 + row) * HIDn + (k0 - Ksplit) + c8, h, l);
            *(short8*)&Ash[row][c8] = h;
            if (alo) *(short8*)&Asl[row][c8] = l;
        }
        // ---- stage B [n][k] 64x32 from pre-transposed hi/lo buffers ----
        {
            const int nn = tid >> 2;         // 0..63
            const int kg = (tid & 3) * 8;    // 0,8,16,24
            const size_t woff = (size_t)(n0 + nn) * K + k0 + kg;
            *(short8*)&Bth[nn][kg] = *(const short8*)(Wth + woff);
            if (WFP) *(short8*)&Btl[nn][kg] = *(const short8*)(Wtl + woff);
        }
        __syncthreads();

        // ---- frag loads ----
        short8 ah[4], bh[2], al[4], bl[2];
        #pragma unroll
        for (int mi = 0; mi < 4; ++mi)
            ah[mi] = *(const short8*)&Ash[wr * 64 + mi * 16 + l15][g * 8];
        #pragma unroll
        for (int ni = 0; ni < 2; ++ni)
            bh[ni] = *(const short8*)&Bth[wc * 32 + ni * 16 + l15][g * 8];
        if (alo) {
            #pragma unroll
            for (int mi = 0; mi < 4; ++mi)
                al[mi] = *(const short8*)&Asl[wr * 64 + mi * 16 + l15][g * 8];
        }
        if (WFP) {
            #pragma unroll
            for (int ni = 0; ni < 2; ++ni)
                bl[ni] = *(const short8*)&Btl[wc * 32 + ni * 16 + l15][g * 8];
        }

        // ---- MFMA: hi*hi always; cross terms when split (round-2 order) ----
        #pragma unroll
        for (int mi = 0; mi < 4; ++mi)
            #pragma unroll
            for (int ni = 0; ni < 2; ++ni)
                acc[mi][ni] = __builtin_amdgcn_mfma_f32_16x16x32_bf16(ah[mi], bh[ni], acc[mi][ni], 0, 0, 0);
        if (WFP) {
            #pragma unroll
            for (int mi = 0; mi < 4; ++mi)
                #pragma unroll
                for (int ni = 0; ni < 2; ++ni)
                    acc[mi][ni] = __builtin_amdgcn_mfma_f32_16x16x32_bf16(ah[mi], bl[ni], acc[mi][ni], 0, 0, 0);
        }
        if (alo) {
            #pragma unroll
            for (int mi = 0; mi < 4; ++mi)
                #pragma unroll
                for (int ni = 0; ni < 2; ++ni)
                    acc[mi][ni] = __builtin_amdgcn_mfma_f32_16x16x32_bf16(al[mi], bh[ni], acc[mi][ni], 0, 0, 0);
        }
        __syncthreads();
    }

    // ---- epilogue: D row = g*4+r, col = l15 (verified m89/m91) ----
    #pragma unroll
    for (int mi = 0; mi < 4; ++mi) {
        #pragma unroll
        for (int ni = 0; ni < 2; ++ni) {
            const int col = n0 + wc * 32 + ni * 16 + l15;
            const float bv = ld1f(bias + col);
            #pragma unroll
            for (int r = 0; r < 4; ++r) {
                const int row = m0 + wr * 64 + mi * 16 + g * 4 + r;
                float v = acc[mi][ni][r] + bv;
                if (gate) {
                    float gt = bf2f(gate[(size_t)row * HIDn + col]);
                    v = v / (1.f + expf(-gt));
                }
                const size_t idx = (size_t)row * HIDn + col;
                if (c_fp32) ((float*)Cv)[idx] = v;
                else        ((unsigned short*)Cv)[idx] = f2bf(v);
            }
        }
    }
}

// ---------------------------------------------------------------------------
// MFMA flash-style attention (round-2 verbatim, passed). Block = 64 q-rows of
// one (b,h); 4 waves x 16 rows. Pass1 online (m,l); pass2 recompute + P + PV.
// ---------------------------------------------------------------------------
#define QB 64
#define KT 128
#define KSTRIDE 72   // Qs/Ks row stride in ushort (144B = 9*16B)
#define VSTRIDE 136  // Vt/Ps row stride in ushort (272B = 17*16B)

__launch_bounds__(256, 2)
__global__ void attn_mfma_kernel(const unsigned short* __restrict__ Q,
                                 const unsigned short* __restrict__ Kb,
                                 const unsigned short* __restrict__ V,
                                 const int* __restrict__ mask,
                                 void* __restrict__ dout,
                                 unsigned short* __restrict__ xout,
                                 const int* __restrict__ flag)
{
    __shared__ __align__(16) unsigned short Qs[QB][KSTRIDE];
    __shared__ __align__(16) unsigned short Ks[KT][KSTRIDE];
    __shared__ __align__(16) unsigned short Vt[HDn][VSTRIDE];
    __shared__ __align__(16) unsigned short Ps[QB][VSTRIDE];
    __shared__ float maskadd[KT];

    const int bid = blockIdx.x;
    const int qb  = bid & 15;
    const int h   = (bid >> 4) % NHn;
    const int b   = (bid >> 4) / NHn;
    const int q0  = qb * QB;

    const int tid  = threadIdx.x;
    const int lane = tid & 63;
    const int wid  = tid >> 6;
    const int l15  = lane & 15;
    const int g    = lane >> 4;
    const int ofp32 = *flag;

    #pragma unroll
    for (int i = 0; i < 2; ++i) {
        const int chunk = i * 256 + tid;
        const int row = chunk >> 3;
        const int c8  = (chunk & 7) * 8;
        uint4 v = *(const uint4*)(Q + ((size_t)(b * Sn + q0 + row)) * HIDn + h * HDn + c8);
        *(uint4*)&Qs[row][c8] = v;
    }
    __syncthreads();

    short8 qa[2];
    #pragma unroll
    for (int ks = 0; ks < 2; ++ks)
        qa[ks] = *(const short8*)&Qs[wid * 16 + l15][ks * 32 + g * 8];

    float mrow[4], lrow[4];
    #pragma unroll
    for (int r = 0; r < 4; ++r) { mrow[r] = -3.0e38f; lrow[r] = 0.f; }

    // ================= pass 1: online (m,l) =================
    #pragma unroll 1
    for (int kt = 0; kt < Sn; kt += KT) {
        __syncthreads();
        #pragma unroll
        for (int i = 0; i < 4; ++i) {
            const int chunk = i * 256 + tid;
            const int row = chunk >> 3;
            const int c8  = (chunk & 7) * 8;
            uint4 v = *(const uint4*)(Kb + ((size_t)(b * Sn + kt + row)) * HIDn + h * HDn + c8);
            *(uint4*)&Ks[row][c8] = v;
        }
        if (tid < KT) maskadd[tid] = (mask[b * Sn + kt + tid] == 0) ? -1e10f : 0.0f;
        __syncthreads();

        f32x4 sacc[8];
        #pragma unroll
        for (int nt = 0; nt < 8; ++nt) sacc[nt] = (f32x4){0.f, 0.f, 0.f, 0.f};
        #pragma unroll
        for (int ks = 0; ks < 2; ++ks) {
            #pragma unroll
            for (int nt = 0; nt < 8; ++nt) {
                short8 kb = *(const short8*)&Ks[nt * 16 + l15][ks * 32 + g * 8];
                sacc[nt] = __builtin_amdgcn_mfma_f32_16x16x32_bf16(qa[ks], kb, sacc[nt], 0, 0, 0);
            }
        }
        #pragma unroll
        for (int r = 0; r < 4; ++r) {
            float sv[8], tmax = -3.0e38f;
            #pragma unroll
            for (int nt = 0; nt < 8; ++nt) {
                sv[nt] = sacc[nt][r] * 0.125f + maskadd[nt * 16 + l15];
                tmax = fmaxf(tmax, sv[nt]);
            }
            const float mnew = fmaxf(mrow[r], tmax);
            float acc = lrow[r] * __expf(mrow[r] - mnew);
            #pragma unroll
            for (int nt = 0; nt < 8; ++nt) acc += __expf(sv[nt] - mnew);
            lrow[r] = acc; mrow[r] = mnew;
        }
    }

    #pragma unroll
    for (int r = 0; r < 4; ++r) {
        float m = mrow[r], l = lrow[r];
        #pragma unroll
        for (int off = 1; off < 16; off <<= 1) {
            const float m2 = __shfl_xor(m, off);
            const float l2 = __shfl_xor(l, off);
            const float mn = fmaxf(m, m2);
            l = l * __expf(m - mn) + l2 * __expf(m2 - mn);
            m = mn;
        }
        mrow[r] = m;
        lrow[r] = 1.0f / l;
    }

    // ================= pass 2: P write + PV =================
    f32x4 xacc[4];
    #pragma unroll
    for (int dt = 0; dt < 4; ++dt) xacc[dt] = (f32x4){0.f, 0.f, 0.f, 0.f};

    #pragma unroll 1
    for (int kt = 0; kt < Sn; kt += KT) {
        __syncthreads();
        #pragma unroll
        for (int i = 0; i < 4; ++i) {
            const int chunk = i * 256 + tid;
            const int row = chunk >> 3;
            const int c8  = (chunk & 7) * 8;
            uint4 v = *(const uint4*)(Kb + ((size_t)(b * Sn + kt + row)) * HIDn + h * HDn + c8);
            *(uint4*)&Ks[row][c8] = v;
        }
        #pragma unroll
        for (int i = 0; i < 4; ++i) {
            const int task = i * 256 + tid;
            const int key = task >> 3;
            const int dg  = (task & 7) * 8;
            uint4 v = *(const uint4*)(V + ((size_t)(b * Sn + kt + key)) * HIDn + h * HDn + dg);
            const unsigned short* us = (const unsigned short*)&v;
            #pragma unroll
            for (int t = 0; t < 8; ++t) Vt[dg + t][key] = us[t];
        }
        if (tid < KT) maskadd[tid] = (mask[b * Sn + kt + tid] == 0) ? -1e10f : 0.0f;
        __syncthreads();

        f32x4 sacc[8];
        #pragma unroll
        for (int nt = 0; nt < 8; ++nt) sacc[nt] = (f32x4){0.f, 0.f, 0.f, 0.f};
        #pragma unroll
        for (int ks = 0; ks < 2; ++ks) {
            #pragma unroll
            for (int nt = 0; nt < 8; ++nt) {
                short8 kb = *(const short8*)&Ks[nt * 16 + l15][ks * 32 + g * 8];
                sacc[nt] = __builtin_amdgcn_mfma_f32_16x16x32_bf16(qa[ks], kb, sacc[nt], 0, 0, 0);
            }
        }

        const size_t arowbase =
            OUT0 + (((size_t)(b * NHn + h)) * Sn + (size_t)(q0 + wid * 16)) * (size_t)Sn;
        #pragma unroll
        for (int r = 0; r < 4; ++r) {
            const int rloc = g * 4 + r;
            #pragma unroll
            for (int nt = 0; nt < 8; ++nt) {
                const int col = nt * 16 + l15;
                const float sv = sacc[nt][r] * 0.125f + maskadd[col];
                const float p  = __expf(sv - mrow[r]) * lrow[r];
                const size_t oidx = arowbase + (size_t)rloc * Sn + kt + col;
                if (ofp32) __builtin_nontemporal_store(p, (float*)dout + oidx);
                else       __builtin_nontemporal_store(f2bf(p), (unsigned short*)dout + oidx);
                Ps[wid * 16 + rloc][col] = f2bf(p);
            }
        }
        short8 pa[4];
        #pragma unroll
        for (int k2 = 0; k2 < 4; ++k2)
            pa[k2] = *(const short8*)&Ps[wid * 16 + l15][k2 * 32 + g * 8];
        #pragma unroll
        for (int dt = 0; dt < 4; ++dt) {
            #pragma unroll
            for (int k2 = 0; k2 < 4; ++k2) {
                short8 vb = *(const short8*)&Vt[dt * 16 + l15][k2 * 32 + g * 8];
                xacc[dt] = __builtin_amdgcn_mfma_f32_16x16x32_bf16(pa[k2], vb, xacc[dt], 0, 0, 0);
            }
        }
    }

    #pragma unroll
    for (int dt = 0; dt < 4; ++dt) {
        #pragma unroll
        for (int r = 0; r < 4; ++r) {
            const int rloc = g * 4 + r;
            const int q = q0 + wid * 16 + rloc;
            const int d = dt * 16 + l15;
            xout[((size_t)(b * Sn + q)) * HIDn + h * HDn + d] = f2bf(xacc[dt][r]);
        }
    }
}

extern "C" void kernel_launch(void* const* d_in, const int* in_sizes, int n_in,
                              void* d_out, int out_size, void* d_ws, size_t ws_size,
                              hipStream_t stream)
{
    const int* mask = (const int*)d_in[3];

    char* ws = (char*)d_ws;
    const size_t SZ = (size_t)MROWS * HIDn * 2;  // 12.58 MB per bf16 [8192,768]
    unsigned short* Qb = (unsigned short*)(ws);
    unsigned short* Kb = (unsigned short*)(ws + SZ);
    unsigned short* Vb = (unsigned short*)(ws + 2 * SZ);
    unsigned short* Xa = (unsigned short*)(ws + 3 * SZ);
    int* flag = (int*)(ws + 4 * SZ);             // total ws: 50.33 MB (round-2-proven)
    unsigned short* Yb = Qb;   // dead after attn
    unsigned short* H1 = Vb;   // dead after attn (Kb slot now holds prep2 W's)

    // prep1 outputs live in the Xa slot until attn overwrites it (QKV W's
    // dead by then). 6 x 589824 ushorts = 7.08 MB <= 12.58 MB slot.
    const size_t W768  = (size_t)HIDn * HIDn;        // 589824
    const size_t W1536 = (size_t)2 * HIDn * HIDn;    // 1179648
    unsigned short* Wqt_h = Xa;
    unsigned short* Wqt_l = Wqt_h + W768;
    unsigned short* Wkt_h = Wqt_l + W768;
    unsigned short* Wkt_l = Wkt_h + W768;
    unsigned short* Wvt_h = Wkt_l + W768;
    unsigned short* Wvt_l = Wvt_h + W768;
    // prep2 outputs live in the Kb slot (dead after attn). 11.8 MB <= 12.58.
    unsigned short* Wot_h = Kb;
    unsigned short* Wot_l = Wot_h + W768;
    unsigned short* W1t_h = Wot_l + W768;
    unsigned short* W1t_l = W1t_h + W1536;
    unsigned short* W2t_h = W1t_l + W1536;
    unsigned short* W2t_l = W2t_h + W1536;

    probe_kernel<<<1, 256, 0, stream>>>((const unsigned short*)d_in[0], flag);

    // ---------- prep1: Wq/Wk/Wv -> transposed hi/lo ----------
    prep_w<<<dim3(12, 12, 3), 256, 0, stream>>>(
        d_in[4], d_in[6], d_in[8],
        Wqt_h, Wqt_l, Wkt_h, Wkt_l, Wvt_h, Wvt_l,
        HIDn, HIDn, HIDn, flag);

    dim3 gg(HIDn / 64, MROWS / 128);  // (12, 64)
    const int BIG = 1 << 30;

    // ---------- QKV projections ----------
    {   // mode 0: bf16 inputs
        typedef unsigned short T;
        gemm_mfma<T,T,T><<<gg,256,0,stream>>>((const T*)d_in[0],(const T*)d_in[0],BIG,HIDn,
            Wqt_h,Wqt_l,(const T*)d_in[5],nullptr,Qb,0,flag,0);
        gemm_mfma<T,T,T><<<gg,256,0,stream>>>((const T*)d_in[1],(const T*)d_in[1],BIG,HIDn,
            Wkt_h,Wkt_l,(const T*)d_in[7],nullptr,Kb,0,flag,0);
        gemm_mfma<T,T,T><<<gg,256,0,stream>>>((const T*)d_in[2],(const T*)d_in[2],BIG,HIDn,
            Wvt_h,Wvt_l,(const T*)d_in[9],nullptr,Vb,0,flag,0);
    }
    {   // mode 1: fp32 inputs (split-precision)
        typedef float T;
        gemm_mfma<T,T,T><<<gg,256,0,stream>>>((const T*)d_in[0],(const T*)d_in[0],BIG,HIDn,
            Wqt_h,Wqt_l,(const T*)d_in[5],nullptr,Qb,0,flag,1);
        gemm_mfma<T,T,T><<<gg,256,0,stream>>>((const T*)d_in[1],(const T*)d_in[1],BIG,HIDn,
            Wkt_h,Wkt_l,(const T*)d_in[7],nullptr,Kb,0,flag,1);
        gemm_mfma<T,T,T><<<gg,256,0,stream>>>((const T*)d_in[2],(const T*)d_in[2],BIG,HIDn,
            Wvt_h,Wvt_l,(const T*)d_in[9],nullptr,Vb,0,flag,1);
    }

    // ---------- attention (round-2 verbatim) ----------
    attn_mfma_kernel<<<Bn * NHn * (Sn / QB), 256, 0, stream>>>(Qb, Kb, Vb, mask, d_out, Xa, flag);

    // ---------- prep2: Wo/W1/W2 -> transposed hi/lo (Kb slot, post-attn) ----------
    prep_w<<<dim3(24, 12, 3), 256, 0, stream>>>(
        d_in[10], d_in[12], d_in[14],
        Wot_h, Wot_l, W1t_h, W1t_l, W2t_h, W2t_l,
        HIDn, 2 * HIDn, 2 * HIDn, flag);

    // ---------- Wo projection + FFN (round-2 structure, H1 in Vb slot) ----------
    {   // mode 0
        typedef unsigned short T;
        gemm_mfma<T,T,T><<<gg,256,0,stream>>>(Xa,Xa,BIG,HIDn,
            Wot_h,Wot_l,(const T*)d_in[11],nullptr,Yb,0,flag,0);
        gemm_mfma<T,T,T><<<gg,256,0,stream>>>(Yb,(const T*)d_in[0],HIDn,2*HIDn,
            W1t_h,W1t_l,(const T*)d_in[13],nullptr,H1,0,flag,0);
        gemm_mfma<T,T,T><<<gg,256,0,stream>>>(Yb,(const T*)d_in[0],HIDn,2*HIDn,
            W2t_h,W2t_l,(const T*)d_in[15],H1,d_out,/*c_fp32=*/0,flag,0);
    }
    {   // mode 1
        typedef float T;
        gemm_mfma<unsigned short,unsigned short,T><<<gg,256,0,stream>>>(Xa,Xa,BIG,HIDn,
            Wot_h,Wot_l,(const T*)d_in[11],nullptr,Yb,0,flag,1);
        gemm_mfma<unsigned short,T,T><<<gg,256,0,stream>>>(Yb,(const T*)d_in[0],HIDn,2*HIDn,
            W1t_h,W1t_l,(const T*)d_in[13],nullptr,H1,0,flag,1);
        gemm_mfma<unsigned short,T,T><<<gg,256,0,stream>>>(Yb,(const T*)d_in[0],HIDn,2*HIDn,
            W2t_h,W2t_l,(const T*)d_in[15],H1,d_out,/*c_fp32=*/1,flag,1);
    }
}